// Round 5
// baseline (109.506 us; speedup 1.0000x reference)
//
#include <hip/hip_runtime.h>
#include <stdint.h>

#define L_DIM 1024
#define N_DIM 64
#define D_DIM 64
#define O_DIM 1024
#define ND    4096              // slice stride (floats) for x / upfold rows
#define NT    8                 // O tiles per team (2 teams x 8 = 16)

typedef float    floatx16 __attribute__((ext_vector_type(16)));
typedef _Float16 half8    __attribute__((ext_vector_type(8)));
typedef _Float16 h2       __attribute__((ext_vector_type(2)));
typedef __fp16   fp16x2   __attribute__((ext_vector_type(2)));

// ---------- pre-converted U image: exact LDS byte image per (n, o-tile) ----------
// [ Ub: 64 rows x 72 halves (144 B, 16B-aligned rows)          = 9216 B ]
// [ UtT: 64 d-rows x 38 u32 (152 B rows; cols = o-pair packed) = 9728 B ]
#define IMG_TILE 19  // placeholder (redefined numerically below)
#undef IMG_TILE
#define UB_BYTES  9216
#define UTT_BYTES 9728
#define IMG_BYTES (UB_BYTES + UTT_BYTES)          // 18944 = 4*4096 + 160*16 exactly
#define WS_NEEDED ((size_t)N_DIM * 16 * IMG_BYTES)

#define BUF_STRIDE_FB 17920     // fallback kernel: Ub 9216 B + Ut2 8704 B

__device__ __forceinline__ uint32_t pkh2(float a, float b) {
    fp16x2 p = __builtin_amdgcn_cvt_pkrtz(a, b);   // v_cvt_pkrtz_f16_f32
    return __builtin_bit_cast(uint32_t, p);
}

__device__ __forceinline__ half8 mk_frag(uint32_t a, uint32_t b, uint32_t c, uint32_t d) {
    union { uint32_t u[4]; half8 v; } U;
    U.u[0] = a; U.u[1] = b; U.u[2] = c; U.u[3] = d;
    return U.v;
}

// sigmoid(s/8) - 0.5 = 0.5*tanh(s/16), odd poly in v=(s/16)^2, packed fp16.
__device__ __forceinline__ uint32_t psig(float s0, float s1) {
    const h2 HI = {(_Float16)41.6f,        (_Float16)41.6f};
    const h2 LO = {(_Float16)-41.6f,       (_Float16)-41.6f};
    const h2 SC = {(_Float16)0.0625f,      (_Float16)0.0625f};
    const h2 C0 = {(_Float16)0.03099238f,  (_Float16)0.03099238f};
    const h2 C1 = {(_Float16)-0.00842090f, (_Float16)-0.00842090f};
    const h2 C2 = {(_Float16)0.00151845f,  (_Float16)0.00151845f};
    const h2 C3 = {(_Float16)-1.02197e-4f, (_Float16)-1.02197e-4f};
    h2 s = __builtin_bit_cast(h2, pkh2(s0, s1));
    s = __builtin_elementwise_min(s, HI);
    s = __builtin_elementwise_max(s, LO);
    h2 ha = s * SC;
    h2 v  = ha * ha;
    h2 w  = C2 + v * C3;
    w     = C1 + v * w;
    w     = C0 + v * w;
    h2 f  = s * w;
    return __builtin_bit_cast(uint32_t, f);
}

// Coalesced U tile load: thread (r8, c) takes rows 2*r8+32j (va) and +1 (vb),
// cols 4c..4c+3.
__device__ __forceinline__ void load_tile(const float* ubase, int ot,
                                          int r8, int c, float4* va, float4* vb) {
    const float* pr = ubase + (size_t)(ot * 64 + 2 * r8) * ND + 4 * c;
    #pragma unroll
    for (int j = 0; j < 2; ++j) {
        va[j] = *(const float4*)(pr + (size_t)(32 * j) * ND);
        vb[j] = *(const float4*)(pr + (size_t)(32 * j) * ND + ND);
    }
}

// async global -> LDS, 16 B per lane, wave-uniform LDS base + lane*16 (HW rule)
__device__ __forceinline__ void gll16(const unsigned char* g, unsigned char* l) {
    __builtin_amdgcn_global_load_lds(
        (const __attribute__((address_space(1))) void*)g,
        (__attribute__((address_space(3))) void*)l, 16, 0, 0);
}

// ================= kernel A: U (f32) -> packed f16 LDS image =================
__global__ void __launch_bounds__(256)
conv_kernel(const float* __restrict__ up, unsigned char* __restrict__ img)
{
    const int tid = threadIdx.x;
    const int r8  = tid >> 4;            // 0..15
    const int c   = tid & 15;
    const int n   = blockIdx.x;
    const int ot  = blockIdx.y;

    const float* ubase = up + (size_t)n * D_DIM;
    float4 va[2], vb[2];
    load_tile(ubase, ot, r8, c, va, vb);

    unsigned char* tb = img + (size_t)(n * 16 + ot) * IMG_BYTES;
    uint16_t (*Ub)[72]  = (uint16_t (*)[72])tb;
    uint32_t (*UtT)[38] = (uint32_t (*)[38])(tb + UB_BYTES);

    #pragma unroll
    for (int j = 0; j < 2; ++j) {
        *(uint2*)&Ub[2*r8 + 32*j][4*c] =
            make_uint2(pkh2(va[j].x, va[j].y), pkh2(va[j].z, va[j].w));
        *(uint2*)&Ub[2*r8 + 32*j + 1][4*c] =
            make_uint2(pkh2(vb[j].x, vb[j].y), pkh2(vb[j].z, vb[j].w));
        const int op = r8 + 16*j;        // o-pair index
        UtT[4*c + 0][op] = pkh2(va[j].x, vb[j].x);
        UtT[4*c + 1][op] = pkh2(va[j].y, vb[j].y);
        UtT[4*c + 2][op] = pkh2(va[j].z, vb[j].z);
        UtT[4*c + 3][op] = pkh2(va[j].w, vb[j].w);
    }
}

// ================= kernel B: main compute, DMA-staged U tiles =================
__global__ void __launch_bounds__(512, 4)
corr_kernel_g(const float* __restrict__ x, const unsigned char* __restrict__ img,
              float* __restrict__ out)
{
    __shared__ __align__(16) unsigned char smem[4 * IMG_BYTES];   // 75776 B

    const int tid  = threadIdx.x;        // 0..511
    const int lane = tid & 63;
    const int wid  = tid >> 6;           // 0..7
    const int team = wid >> 2;           // 0 / 1: O-half
    const int tw   = wid & 3;            // wave within team (l row-group)
    const int l31  = lane & 31;
    const int h    = lane >> 5;          // wave half
    const int ttid = tid & 255;          // thread within team
    const int n    = blockIdx.x;         // XCD affinity: bid%8 = n%8
    const int lb   = blockIdx.y;
    const int lw   = lb * 128 + tw * 32 + l31;    // this lane's l row

    const int ob = team * NT;            // first O tile of this team
    unsigned char* tsmem = smem + team * 2 * IMG_BYTES;
    const unsigned char* gimg = img + (size_t)n * 16 * IMG_BYTES;

    // ---- phase 0: coalesced X tile (128 rows) -> LDS fp32, build Xf frags ----
    half8 Xf[4];
    {
        float (*Xs)[68] = (float (*)[68])smem;     // 128 x 68 f32 = 34816 B overlay
        const int xr = tid >> 2;                   // row 0..127
        const int xq = tid & 3;                    // quarter-row
        const float* xsrc = x + (size_t)(lb * 128 + xr) * ND + n * D_DIM;
        #pragma unroll
        for (int j = 0; j < 4; ++j) {
            const int f4i = xq * 4 + j;
            *(float4*)&Xs[xr][4 * f4i] = *(const float4*)(xsrc + 4 * f4i);
        }
        __syncthreads();
        const int rl = tw * 32 + l31;
        #pragma unroll
        for (int kk = 0; kk < 4; ++kk) {
            float4 f1 = *(const float4*)&Xs[rl][16 * kk + 8 * h];
            float4 f2 = *(const float4*)&Xs[rl][16 * kk + 8 * h + 4];
            Xf[kk] = mk_frag(pkh2(f1.x, f1.y), pkh2(f1.z, f1.w),
                             pkh2(f2.x, f2.y), pkh2(f2.z, f2.w));
        }
        __syncthreads();   // protect Xs before DMA staging overwrites it
    }

    // ---- DMA-stage tile ob+0 into team buffer 0 ----
    {
        const unsigned char* g0 = gimg + (size_t)ob * IMG_BYTES;
        #pragma unroll
        for (int i = 0; i < 4; ++i)
            gll16(g0 + ttid * 16 + i * 4096, tsmem + tw * 1024 + i * 4096);
        if (ttid < 160)
            gll16(g0 + ttid * 16 + 16384, tsmem + tw * 1024 + 16384);
    }
    __syncthreads();   // implicit vmcnt(0): tile 0 resident

    floatx16 F0, F1;   // F^T accumulators, d 0..31 / 32..63
    #pragma unroll
    for (int i = 0; i < 16; ++i) { F0[i] = 0.0f; F1[i] = 0.0f; }

    for (int ot = 0; ot < NT; ++ot) {
        const int b = ot & 1;
        const unsigned char* bufc = tsmem + b * IMG_BYTES;
        unsigned char*       bufn = tsmem + (b ^ 1) * IMG_BYTES;
        const uint16_t (*Ub)[72] = (const uint16_t (*)[72])bufc;
        const uint32_t* utT      = (const uint32_t*)(bufc + UB_BYTES);

        // issue next-tile DMA first (latency hidden under this tile's compute)
        if (ot + 1 < NT) {
            const unsigned char* gn = gimg + (size_t)(ob + ot + 1) * IMG_BYTES;
            #pragma unroll
            for (int i = 0; i < 4; ++i)
                gll16(gn + ttid * 16 + i * 4096, bufn + tw * 1024 + i * 4096);
            if (ttid < 160)
                gll16(gn + ttid * 16 + 16384, bufn + tw * 1024 + 16384);
        }

        // ---- GEMM1 A-frags: b128 reads of row-major Ub ----
        half8 A0k[4], A1k[4];
        #pragma unroll
        for (int kk = 0; kk < 4; ++kk) {
            A0k[kk] = *(const half8*)&Ub[l31][16 * kk + 8 * h];
            A1k[kk] = *(const half8*)&Ub[32 + l31][16 * kk + 8 * h];
        }

        // ---- GEMM1: S^T = U * X^T   (M=o, N=l, K=d) ----
        floatx16 S0, S1;
        #pragma unroll
        for (int i = 0; i < 16; ++i) { S0[i] = 0.0f; S1[i] = 0.0f; }
        #pragma unroll
        for (int kk = 0; kk < 4; ++kk) {
            S0 = __builtin_amdgcn_mfma_f32_32x32x16_f16(A0k[kk], Xf[kk], S0, 0, 0, 0);
            S1 = __builtin_amdgcn_mfma_f32_32x32x16_f16(A1k[kk], Xf[kk], S1, 0, 0, 0);
        }

        // ---- sigmoid weights: packed-fp16 odd polynomial ----
        uint32_t P[16];
        #pragma unroll
        for (int m = 0; m < 8; ++m) P[m]     = psig(S0[2*m], S0[2*m+1]);
        #pragma unroll
        for (int m = 0; m < 8; ++m) P[8 + m] = psig(S1[2*m], S1[2*m+1]);

        // ---- GEMM2: F^T += U^T * W — shuffles hoisted ahead of MFMA chain ----
        uint32_t R[8];
        #pragma unroll
        for (int c2 = 0; c2 < 4; ++c2) {
            const uint32_t* Q = P + (c2 >> 1) * 8;
            const int t4 = (c2 & 1) * 4;
            R[2*c2]   = __shfl_xor(h ? Q[t4]     : Q[t4 + 2], 32);
            R[2*c2+1] = __shfl_xor(h ? Q[t4 + 1] : Q[t4 + 3], 32);
        }
        #pragma unroll
        for (int c2 = 0; c2 < 4; ++c2) {
            const uint32_t* Q = P + (c2 >> 1) * 8;
            const int t4 = (c2 & 1) * 4;
            half8 B = h ? mk_frag(R[2*c2], R[2*c2+1], Q[t4 + 2], Q[t4 + 3])
                        : mk_frag(Q[t4], Q[t4 + 1], R[2*c2], R[2*c2+1]);
            // A-frags: d-major UtT rows, contiguous o-pairs -> two b64 per frag
            const int opb = 8 * c2 + 4 * h;
            const uint32_t* r0 = utT + l31 * 38;
            const uint32_t* r1 = utT + (32 + l31) * 38;
            uint2 q0 = *(const uint2*)(r0 + opb);
            uint2 q1 = *(const uint2*)(r0 + opb + 2);
            uint2 q2 = *(const uint2*)(r1 + opb);
            uint2 q3 = *(const uint2*)(r1 + opb + 2);
            half8 A0 = mk_frag(q0.x, q0.y, q1.x, q1.y);
            half8 A1 = mk_frag(q2.x, q2.y, q3.x, q3.y);
            F0 = __builtin_amdgcn_mfma_f32_32x32x16_f16(A0, B, F0, 0, 0, 0);
            F1 = __builtin_amdgcn_mfma_f32_32x32x16_f16(A1, B, F1, 0, 0, 0);
        }
        __syncthreads();   // drains next-tile DMA (vmcnt) + protects buffers
    }

    // ---- epilogue: in-block team combine via LDS, then direct store ----
    {
        float (*Fs)[68] = (float (*)[68])smem;   // 128 x 68 f32 overlay
        const int row = tw * 32 + l31;
        if (team == 1) {
            #pragma unroll
            for (int q = 0; q < 4; ++q) {
                float4 a; a.x = F0[4*q]; a.y = F0[4*q+1]; a.z = F0[4*q+2]; a.w = F0[4*q+3];
                *(float4*)&Fs[row][8*q + 4*h] = a;            // d 0..31
                float4 bq; bq.x = F1[4*q]; bq.y = F1[4*q+1]; bq.z = F1[4*q+2]; bq.w = F1[4*q+3];
                *(float4*)&Fs[row][32 + 8*q + 4*h] = bq;      // d 32..63
            }
        }
        __syncthreads();
        if (team == 0) {
            float* op = out + (size_t)lw * ND + n * D_DIM;
            #pragma unroll
            for (int q = 0; q < 4; ++q) {
                float4 t0 = *(const float4*)&Fs[row][8*q + 4*h];
                float4 a; a.x = F0[4*q]   + t0.x; a.y = F0[4*q+1] + t0.y;
                          a.z = F0[4*q+2] + t0.z; a.w = F0[4*q+3] + t0.w;
                *(float4*)(op + 8*q + 4*h) = a;               // d 0..31
                float4 t1 = *(const float4*)&Fs[row][32 + 8*q + 4*h];
                float4 bq; bq.x = F1[4*q]   + t1.x; bq.y = F1[4*q+1] + t1.y;
                           bq.z = F1[4*q+2] + t1.z; bq.w = F1[4*q+3] + t1.w;
                *(float4*)(op + 32 + 8*q + 4*h) = bq;         // d 32..63
            }
        }
    }
}

// ================= fallback (round-3 kernel, verbatim): used if ws too small =================
__global__ void __launch_bounds__(512, 4)
corr_kernel_fb(const float* __restrict__ x, const float* __restrict__ up,
               float* __restrict__ out)
{
    __shared__ __align__(16) unsigned char smem[4 * BUF_STRIDE_FB];

    const int tid  = threadIdx.x;
    const int lane = tid & 63;
    const int wid  = tid >> 6;
    const int team = wid >> 2;
    const int tw   = wid & 3;
    const int l31  = lane & 31;
    const int h    = lane >> 5;
    const int ttid = tid & 255;
    const int r8   = ttid >> 4;
    const int c    = ttid & 15;
    const int n    = blockIdx.x;
    const int lb   = blockIdx.y;
    const int lw   = lb * 128 + tw * 32 + l31;

    const float* ubase = up + (size_t)n * D_DIM;
    const int ob = team * NT;
    unsigned char* tsmem = smem + team * 2 * BUF_STRIDE_FB;

    float4 va[2], vb[2];
    load_tile(ubase, ob + 0, r8, c, va, vb);

    half8 Xf[4];
    {
        float (*Xs)[68] = (float (*)[68])smem;
        const int xr = tid >> 2;
        const int xq = tid & 3;
        const float* xsrc = x + (size_t)(lb * 128 + xr) * ND + n * D_DIM;
        #pragma unroll
        for (int j = 0; j < 4; ++j) {
            const int f4i = xq * 4 + j;
            *(float4*)&Xs[xr][4 * f4i] = *(const float4*)(xsrc + 4 * f4i);
        }
        __syncthreads();
        const int rl = tw * 32 + l31;
        #pragma unroll
        for (int kk = 0; kk < 4; ++kk) {
            float4 f1 = *(const float4*)&Xs[rl][16 * kk + 8 * h];
            float4 f2 = *(const float4*)&Xs[rl][16 * kk + 8 * h + 4];
            Xf[kk] = mk_frag(pkh2(f1.x, f1.y), pkh2(f1.z, f1.w),
                             pkh2(f2.x, f2.y), pkh2(f2.z, f2.w));
        }
        __syncthreads();
    }

    #pragma unroll
    for (int j = 0; j < 2; ++j) {
        uint16_t (*Ub)[72]  = (uint16_t (*)[72])(tsmem);
        uint32_t (*Ut2)[68] = (uint32_t (*)[68])(tsmem + 9216);
        *(uint2*)&Ub[2*r8 + 32*j][4*c] =
            make_uint2(pkh2(va[j].x, va[j].y), pkh2(va[j].z, va[j].w));
        *(uint2*)&Ub[2*r8 + 32*j + 1][4*c] =
            make_uint2(pkh2(vb[j].x, vb[j].y), pkh2(vb[j].z, vb[j].w));
        *(uint4*)&Ut2[r8 + 16*j][4*c] =
            make_uint4(pkh2(va[j].x, vb[j].x), pkh2(va[j].y, vb[j].y),
                       pkh2(va[j].z, vb[j].z), pkh2(va[j].w, vb[j].w));
    }
    load_tile(ubase, ob + 1, r8, c, va, vb);
    __syncthreads();

    floatx16 F0, F1;
    #pragma unroll
    for (int i = 0; i < 16; ++i) { F0[i] = 0.0f; F1[i] = 0.0f; }

    for (int ot = 0; ot < NT; ++ot) {
        const int b = ot & 1;
        uint16_t (*Ub)[72]   = (uint16_t (*)[72])(tsmem + b * BUF_STRIDE_FB);
        const uint32_t* utp  = (const uint32_t*)(tsmem + b * BUF_STRIDE_FB + 9216);
        uint16_t (*Ubn)[72]  = (uint16_t (*)[72])(tsmem + (b ^ 1) * BUF_STRIDE_FB);
        uint32_t (*Ut2n)[68] = (uint32_t (*)[68])(tsmem + (b ^ 1) * BUF_STRIDE_FB + 9216);

        half8 A0k[4], A1k[4];
        #pragma unroll
        for (int kk = 0; kk < 4; ++kk) {
            A0k[kk] = *(const half8*)&Ub[l31][16 * kk + 8 * h];
            A1k[kk] = *(const half8*)&Ub[32 + l31][16 * kk + 8 * h];
        }

        if (ot + 1 < NT) {
            #pragma unroll
            for (int j = 0; j < 2; ++j) {
                *(uint2*)&Ubn[2*r8 + 32*j][4*c] =
                    make_uint2(pkh2(va[j].x, va[j].y), pkh2(va[j].z, va[j].w));
                *(uint2*)&Ubn[2*r8 + 32*j + 1][4*c] =
                    make_uint2(pkh2(vb[j].x, vb[j].y), pkh2(vb[j].z, vb[j].w));
                *(uint4*)&Ut2n[r8 + 16*j][4*c] =
                    make_uint4(pkh2(va[j].x, vb[j].x), pkh2(va[j].y, vb[j].y),
                               pkh2(va[j].z, vb[j].z), pkh2(va[j].w, vb[j].w));
            }
        }
        if (ot + 2 < NT)
            load_tile(ubase, ob + ot + 2, r8, c, va, vb);

        floatx16 S0, S1;
        #pragma unroll
        for (int i = 0; i < 16; ++i) { S0[i] = 0.0f; S1[i] = 0.0f; }
        #pragma unroll
        for (int kk = 0; kk < 4; ++kk) {
            S0 = __builtin_amdgcn_mfma_f32_32x32x16_f16(A0k[kk], Xf[kk], S0, 0, 0, 0);
            S1 = __builtin_amdgcn_mfma_f32_32x32x16_f16(A1k[kk], Xf[kk], S1, 0, 0, 0);
        }

        uint32_t P[16];
        #pragma unroll
        for (int m = 0; m < 8; ++m) P[m]     = psig(S0[2*m], S0[2*m+1]);
        #pragma unroll
        for (int m = 0; m < 8; ++m) P[8 + m] = psig(S1[2*m], S1[2*m+1]);

        uint32_t R[8];
        #pragma unroll
        for (int c2 = 0; c2 < 4; ++c2) {
            const uint32_t* Q = P + (c2 >> 1) * 8;
            const int t4 = (c2 & 1) * 4;
            R[2*c2]   = __shfl_xor(h ? Q[t4]     : Q[t4 + 2], 32);
            R[2*c2+1] = __shfl_xor(h ? Q[t4 + 1] : Q[t4 + 3], 32);
        }
        #pragma unroll
        for (int c2 = 0; c2 < 4; ++c2) {
            const uint32_t* Q = P + (c2 >> 1) * 8;
            const int t4 = (c2 & 1) * 4;
            half8 B = h ? mk_frag(R[2*c2], R[2*c2+1], Q[t4 + 2], Q[t4 + 3])
                        : mk_frag(Q[t4], Q[t4 + 1], R[2*c2], R[2*c2+1]);
            const int opb = 8 * c2 + 4 * h;
            uint32_t a0[4], a1[4];
            #pragma unroll
            for (int k = 0; k < 4; ++k) {
                a0[k] = utp[(opb + k) * 68 + l31];
                a1[k] = utp[(opb + k) * 68 + 32 + l31];
            }
            half8 A0 = mk_frag(a0[0], a0[1], a0[2], a0[3]);
            half8 A1 = mk_frag(a1[0], a1[1], a1[2], a1[3]);
            F0 = __builtin_amdgcn_mfma_f32_32x32x16_f16(A0, B, F0, 0, 0, 0);
            F1 = __builtin_amdgcn_mfma_f32_32x32x16_f16(A1, B, F1, 0, 0, 0);
        }
        __syncthreads();
    }

    {
        float (*Fs)[68] = (float (*)[68])smem;
        const int row = tw * 32 + l31;
        if (team == 1) {
            #pragma unroll
            for (int q = 0; q < 4; ++q) {
                float4 a; a.x = F0[4*q]; a.y = F0[4*q+1]; a.z = F0[4*q+2]; a.w = F0[4*q+3];
                *(float4*)&Fs[row][8*q + 4*h] = a;
                float4 bq; bq.x = F1[4*q]; bq.y = F1[4*q+1]; bq.z = F1[4*q+2]; bq.w = F1[4*q+3];
                *(float4*)&Fs[row][32 + 8*q + 4*h] = bq;
            }
        }
        __syncthreads();
        if (team == 0) {
            float* op = out + (size_t)lw * ND + n * D_DIM;
            #pragma unroll
            for (int q = 0; q < 4; ++q) {
                float4 t0 = *(const float4*)&Fs[row][8*q + 4*h];
                float4 a; a.x = F0[4*q]   + t0.x; a.y = F0[4*q+1] + t0.y;
                          a.z = F0[4*q+2] + t0.z; a.w = F0[4*q+3] + t0.w;
                *(float4*)(op + 8*q + 4*h) = a;
                float4 t1 = *(const float4*)&Fs[row][32 + 8*q + 4*h];
                float4 bq; bq.x = F1[4*q]   + t1.x; bq.y = F1[4*q+1] + t1.y;
                           bq.z = F1[4*q+2] + t1.z; bq.w = F1[4*q+3] + t1.w;
                *(float4*)(op + 32 + 8*q + 4*h) = bq;
            }
        }
    }
}

extern "C" void kernel_launch(void* const* d_in, const int* in_sizes, int n_in,
                              void* d_out, int out_size, void* d_ws, size_t ws_size,
                              hipStream_t stream)
{
    const float* x  = (const float*)d_in[0];
    const float* up = (const float*)d_in[1];
    float* out      = (float*)d_out;

    if (d_ws != nullptr && ws_size >= WS_NEEDED) {
        unsigned char* img = (unsigned char*)d_ws;
        conv_kernel<<<dim3(N_DIM, 16), dim3(256), 0, stream>>>(up, img);
        corr_kernel_g<<<dim3(N_DIM, L_DIM / 128), dim3(512), 0, stream>>>(x, img, out);
    } else {
        corr_kernel_fb<<<dim3(N_DIM, L_DIM / 128), dim3(512), 0, stream>>>(x, up, out);
    }
}

// Round 6
// 101.866 us; speedup vs baseline: 1.0750x; 1.0750x over previous
//
#include <hip/hip_runtime.h>
#include <stdint.h>

#define L_DIM 1024
#define N_DIM 64
#define D_DIM 64
#define O_DIM 1024
#define ND    4096              // slice stride (floats) for x / upfold rows

// U tile image (per 64-o tile): [Ub 64x72 halves | UtT 64 d-rows x 38 u32]
#define UB_BYTES  9216
#define UTT_BYTES 9728
#define IMG_BYTES (UB_BYTES + UTT_BYTES)   // 18944
#define SPAN      4                         // tiles per span
#define NSPAN     4                         // 4 spans x 4 tiles = 16 O-tiles
#define BUF_BYTES (SPAN * IMG_BYTES)        // 75776
#define SMEM_BYTES (2 * BUF_BYTES)          // 151552 <= 160 KiB/CU

typedef float    floatx16 __attribute__((ext_vector_type(16)));
typedef _Float16 half8    __attribute__((ext_vector_type(8)));
typedef _Float16 h2       __attribute__((ext_vector_type(2)));
typedef __fp16   fp16x2   __attribute__((ext_vector_type(2)));

__device__ __forceinline__ uint32_t pkh2(float a, float b) {
    fp16x2 p = __builtin_amdgcn_cvt_pkrtz(a, b);   // v_cvt_pkrtz_f16_f32
    return __builtin_bit_cast(uint32_t, p);
}

__device__ __forceinline__ half8 mk_frag(uint32_t a, uint32_t b, uint32_t c, uint32_t d) {
    union { uint32_t u[4]; half8 v; } U;
    U.u[0] = a; U.u[1] = b; U.u[2] = c; U.u[3] = d;
    return U.v;
}

// sigmoid(s/8) - 0.5 = 0.5*tanh(s/16), odd poly in v=(s/16)^2, packed fp16.
__device__ __forceinline__ uint32_t psig(float s0, float s1) {
    const h2 HI = {(_Float16)41.6f,        (_Float16)41.6f};
    const h2 LO = {(_Float16)-41.6f,       (_Float16)-41.6f};
    const h2 SC = {(_Float16)0.0625f,      (_Float16)0.0625f};
    const h2 C0 = {(_Float16)0.03099238f,  (_Float16)0.03099238f};
    const h2 C1 = {(_Float16)-0.00842090f, (_Float16)-0.00842090f};
    const h2 C2 = {(_Float16)0.00151845f,  (_Float16)0.00151845f};
    const h2 C3 = {(_Float16)-1.02197e-4f, (_Float16)-1.02197e-4f};
    h2 s = __builtin_bit_cast(h2, pkh2(s0, s1));
    s = __builtin_elementwise_min(s, HI);
    s = __builtin_elementwise_max(s, LO);
    h2 ha = s * SC;
    h2 v  = ha * ha;
    h2 w  = C2 + v * C3;
    w     = C1 + v * w;
    w     = C0 + v * w;
    h2 f  = s * w;
    return __builtin_bit_cast(uint32_t, f);
}

// Coalesced U tile load: thread (r8, c) takes rows 2*r8+32j (va) and +1 (vb),
// cols 4c..4c+3.
__device__ __forceinline__ void load_tile(const float* ubase, int ot,
                                          int r8, int c, float4* va, float4* vb) {
    const float* pr = ubase + (size_t)(ot * 64 + 2 * r8) * ND + 4 * c;
    #pragma unroll
    for (int j = 0; j < 2; ++j) {
        va[j] = *(const float4*)(pr + (size_t)(32 * j) * ND);
        vb[j] = *(const float4*)(pr + (size_t)(32 * j) * ND + ND);
    }
}

// pack one tile's registers into its LDS image slot (Ub + UtT), conv-verified layout
__device__ __forceinline__ void pack_tile(unsigned char* tb, int r8, int c,
                                          const float4* va, const float4* vb) {
    uint16_t (*Ub)[72]  = (uint16_t (*)[72])tb;
    uint32_t (*UtT)[38] = (uint32_t (*)[38])(tb + UB_BYTES);
    #pragma unroll
    for (int j = 0; j < 2; ++j) {
        *(uint2*)&Ub[2*r8 + 32*j][4*c] =
            make_uint2(pkh2(va[j].x, va[j].y), pkh2(va[j].z, va[j].w));
        *(uint2*)&Ub[2*r8 + 32*j + 1][4*c] =
            make_uint2(pkh2(vb[j].x, vb[j].y), pkh2(vb[j].z, vb[j].w));
        const int op = r8 + 16*j;
        UtT[4*c + 0][op] = pkh2(va[j].x, vb[j].x);
        UtT[4*c + 1][op] = pkh2(va[j].y, vb[j].y);
        UtT[4*c + 2][op] = pkh2(va[j].z, vb[j].z);
        UtT[4*c + 3][op] = pkh2(va[j].w, vb[j].w);
    }
}

__global__ void __launch_bounds__(512, 2)
corr_kernel(const float* __restrict__ x, const float* __restrict__ up,
            float* __restrict__ out)
{
    __shared__ __align__(16) unsigned char smem[SMEM_BYTES];   // 151552 B, 1 block/CU

    const int tid  = threadIdx.x;        // 0..511
    const int lane = tid & 63;
    const int wid  = tid >> 6;           // 0..7
    const int l31  = lane & 31;
    const int h    = lane >> 5;          // wave half
    const int sid  = tid >> 8;           // staging half: tiles {2sid, 2sid+1} of each span
    const int ttid = tid & 255;
    const int r8   = ttid >> 4;          // staging row-group (0..15)
    const int c    = ttid & 15;          // staging col quad
    const int n    = blockIdx.x;         // bid%8 == n%8 -> same-n blocks share an XCD L2
    const int lb   = blockIdx.y;         // L-tile of 256 rows
    const int lw   = lb * 256 + wid * 32 + l31;   // this lane's l row
    // stagger: waves sharing a SIMD (wid, wid+4) start 2 tiles apart in the span
    const int stoff = (((wid >> 2) * 2) + (wid & 3)) & 3;

    const float* ubase = up + (size_t)n * D_DIM;

    // ---- phase 0: X tile (256 rows) -> LDS fp32 overlay, build Xf frags ----
    half8 Xf[4];
    {
        float (*Xs)[68] = (float (*)[68])smem;     // 256 x 68 f32 = 69632 B overlay
        const int xr = tid >> 1;                   // row 0..255
        const int xh = tid & 1;
        const float* xsrc = x + (size_t)(lb * 256 + xr) * ND + n * D_DIM;
        #pragma unroll
        for (int j = 0; j < 8; ++j) {
            const int f4i = xh * 8 + j;
            *(float4*)&Xs[xr][4 * f4i] = *(const float4*)(xsrc + 4 * f4i);
        }
        __syncthreads();
        const int rl = wid * 32 + l31;
        #pragma unroll
        for (int kk = 0; kk < 4; ++kk) {
            float4 f1 = *(const float4*)&Xs[rl][16 * kk + 8 * h];
            float4 f2 = *(const float4*)&Xs[rl][16 * kk + 8 * h + 4];
            Xf[kk] = mk_frag(pkh2(f1.x, f1.y), pkh2(f1.z, f1.w),
                             pkh2(f2.x, f2.y), pkh2(f2.z, f2.w));
        }
        __syncthreads();   // protect Xs before span-0 pack overwrites it
    }

    // ---- prologue: load+pack span 0 into buf0; load span 1 into regs ----
    float4 va[2][2], vb[2][2];
    #pragma unroll
    for (int k = 0; k < 2; ++k)
        load_tile(ubase, 2*sid + k, r8, c, va[k], vb[k]);
    #pragma unroll
    for (int k = 0; k < 2; ++k)
        pack_tile(smem + (size_t)(2*sid + k) * IMG_BYTES, r8, c, va[k], vb[k]);
    #pragma unroll
    for (int k = 0; k < 2; ++k)
        load_tile(ubase, SPAN + 2*sid + k, r8, c, va[k], vb[k]);
    __syncthreads();

    floatx16 F0, F1;   // F^T accumulators, d 0..31 / 32..63 (full O sweep -> no combine)
    #pragma unroll
    for (int i = 0; i < 16; ++i) { F0[i] = 0.0f; F1[i] = 0.0f; }

    for (int s = 0; s < NSPAN; ++s) {
        const unsigned char* bufc = smem + (size_t)(s & 1) * BUF_BYTES;
        unsigned char*       bufn = smem + (size_t)((s & 1) ^ 1) * BUF_BYTES;

        #pragma unroll
        for (int i = 0; i < SPAN; ++i) {
            // staging chunks: even waves at i={0,2}, odd waves at i={1,3} (time-skew)
            if (s + 1 < NSPAN) {
                #pragma unroll
                for (int k = 0; k < 2; ++k) {
                    if (i == 2*k + (wid & 1)) {
                        pack_tile(bufn + (size_t)(2*sid + k) * IMG_BYTES,
                                  r8, c, va[k], vb[k]);
                        if (s + 2 < NSPAN)
                            load_tile(ubase, (s + 2) * SPAN + 2*sid + k,
                                      r8, c, va[k], vb[k]);
                    }
                }
            }

            const int ti = (stoff + i) & 3;      // this wave's tile within the span
            const unsigned char* tb = bufc + (size_t)ti * IMG_BYTES;
            const uint16_t (*Ub)[72] = (const uint16_t (*)[72])tb;
            const uint32_t* utT      = (const uint32_t*)(tb + UB_BYTES);

            // ---- GEMM1 A-frags: b128 reads of row-major Ub ----
            half8 A0k[4], A1k[4];
            #pragma unroll
            for (int kk = 0; kk < 4; ++kk) {
                A0k[kk] = *(const half8*)&Ub[l31][16 * kk + 8 * h];
                A1k[kk] = *(const half8*)&Ub[32 + l31][16 * kk + 8 * h];
            }

            // ---- GEMM1: S^T = U * X^T   (M=o, N=l, K=d) ----
            floatx16 S0, S1;
            #pragma unroll
            for (int i2 = 0; i2 < 16; ++i2) { S0[i2] = 0.0f; S1[i2] = 0.0f; }
            #pragma unroll
            for (int kk = 0; kk < 4; ++kk) {
                S0 = __builtin_amdgcn_mfma_f32_32x32x16_f16(A0k[kk], Xf[kk], S0, 0, 0, 0);
                S1 = __builtin_amdgcn_mfma_f32_32x32x16_f16(A1k[kk], Xf[kk], S1, 0, 0, 0);
            }

            // ---- sigmoid weights: packed-fp16 odd polynomial ----
            uint32_t P[16];
            #pragma unroll
            for (int m = 0; m < 8; ++m) P[m]     = psig(S0[2*m], S0[2*m+1]);
            #pragma unroll
            for (int m = 0; m < 8; ++m) P[8 + m] = psig(S1[2*m], S1[2*m+1]);

            // ---- GEMM2: F^T += U^T * W — shuffles hoisted ahead of MFMA chain ----
            uint32_t R[8];
            #pragma unroll
            for (int c2 = 0; c2 < 4; ++c2) {
                const uint32_t* Q = P + (c2 >> 1) * 8;
                const int t4 = (c2 & 1) * 4;
                R[2*c2]   = __shfl_xor(h ? Q[t4]     : Q[t4 + 2], 32);
                R[2*c2+1] = __shfl_xor(h ? Q[t4 + 1] : Q[t4 + 3], 32);
            }
            #pragma unroll
            for (int c2 = 0; c2 < 4; ++c2) {
                const uint32_t* Q = P + (c2 >> 1) * 8;
                const int t4 = (c2 & 1) * 4;
                half8 B = h ? mk_frag(R[2*c2], R[2*c2+1], Q[t4 + 2], Q[t4 + 3])
                            : mk_frag(Q[t4], Q[t4 + 1], R[2*c2], R[2*c2+1]);
                // A-frags: d-major UtT rows, contiguous o-pairs -> two b64 per frag
                const int opb = 8 * c2 + 4 * h;
                const uint32_t* r0 = utT + l31 * 38;
                const uint32_t* r1 = utT + (32 + l31) * 38;
                uint2 q0 = *(const uint2*)(r0 + opb);
                uint2 q1 = *(const uint2*)(r0 + opb + 2);
                uint2 q2 = *(const uint2*)(r1 + opb);
                uint2 q3 = *(const uint2*)(r1 + opb + 2);
                half8 A0 = mk_frag(q0.x, q0.y, q1.x, q1.y);
                half8 A1 = mk_frag(q2.x, q2.y, q3.x, q3.y);
                F0 = __builtin_amdgcn_mfma_f32_32x32x16_f16(A0, B, F0, 0, 0, 0);
                F1 = __builtin_amdgcn_mfma_f32_32x32x16_f16(A1, B, F1, 0, 0, 0);
            }
            // NO barrier here: waves free-run across the span's 4 tiles
        }
        __syncthreads();   // one barrier per span: publishes bufn, frees bufc
    }

    // ---- epilogue: full-O accumulators -> direct coalesced store ----
    float* op = out + (size_t)lw * ND + n * D_DIM;
    #pragma unroll
    for (int q = 0; q < 4; ++q) {
        float4 a; a.x = F0[4*q]; a.y = F0[4*q+1]; a.z = F0[4*q+2]; a.w = F0[4*q+3];
        *(float4*)(op + 8*q + 4*h) = a;               // d 0..31
        float4 bq; bq.x = F1[4*q]; bq.y = F1[4*q+1]; bq.z = F1[4*q+2]; bq.w = F1[4*q+3];
        *(float4*)(op + 32 + 8*q + 4*h) = bq;         // d 32..63
    }
}

extern "C" void kernel_launch(void* const* d_in, const int* in_sizes, int n_in,
                              void* d_out, int out_size, void* d_ws, size_t ws_size,
                              hipStream_t stream)
{
    const float* x  = (const float*)d_in[0];
    const float* up = (const float*)d_in[1];
    float* out      = (float*)d_out;
    dim3 grid(N_DIM, L_DIM / 256);   // 256 blocks = 1 per CU; bid%8 = n%8 (XCD affinity)
    corr_kernel<<<grid, dim3(512), 0, stream>>>(x, up, out);
}